// Round 7
// baseline (149.509 us; speedup 1.0000x reference)
//
#include <hip/hip_runtime.h>
#include <hip/hip_bf16.h>

#define CCH 384
#define HW2 3136
#define HH 56
#define WW 56
#define QMAX 7.0f
#define SCALE_MIN 2e-16f
#define PB 49            // 64-pos blocks per image
#define YSLAB 512        // elems per (pb,c8) slab: 64 pos * 8 ci
#define YPB 24576        // 48 * 512 elems per pos-block
#define ROWP 60          // padded LDS row stride (floats)
#define CHF 1024         // per-channel LDS floats (256 quads)

typedef _Float16 half8 __attribute__((ext_vector_type(8)));
typedef float f32x4 __attribute__((ext_vector_type(4)));

#define GLOAD_LDS16(g, l) __builtin_amdgcn_global_load_lds( \
    (const __attribute__((address_space(1))) void*)(g), \
    (__attribute__((address_space(3))) void*)(l), 16, 0, 0)

// ---------------- quant kernels (Brevitas per-channel symmetric int4) -------
// quant_dw also zeroes the 4KB zero-page used by dw staging pads.

__global__ void quant_dw(const float* __restrict__ dw, float* __restrict__ dwq,
                         float* __restrict__ zpg) {
    int tid = threadIdx.x;
    if (blockIdx.x == 0)
        *(f32x4*)&zpg[tid * 4] = (f32x4){0.f, 0.f, 0.f, 0.f};   // 1024 floats

    int c = blockIdx.x * blockDim.x + tid;
    if (c >= CCH) return;
    float w[9];
    float amax = 0.f;
    #pragma unroll
    for (int j = 0; j < 9; ++j) {
        w[j] = dw[c * 9 + j];
        amax = fmaxf(amax, fabsf(w[j]));
    }
    float scale = fmaxf(amax / QMAX, SCALE_MIN);
    #pragma unroll
    for (int j = 0; j < 9; ++j) {
        float q = rintf(w[j] / scale);          // round half-even = jnp.round
        q = fminf(fmaxf(q, -QMAX), QMAX);
        dwq[c * 9 + j] = q * scale;
    }
}

// one block (64 threads) per output channel; fake-quant then pack fp16 into
// MFMA fragment layout: wpk[(ci/32)*24 + co/16][lane][8]
__global__ void quant_pw(const float* __restrict__ pw, _Float16* __restrict__ wpk) {
    int co = blockIdx.x;
    int lane = threadIdx.x;
    float w[6];
    float amax = 0.f;
    #pragma unroll
    for (int j = 0; j < 6; ++j) {
        w[j] = pw[co * CCH + lane + j * 64];
        amax = fmaxf(amax, fabsf(w[j]));
    }
    #pragma unroll
    for (int off = 32; off >= 1; off >>= 1)
        amax = fmaxf(amax, __shfl_xor(amax, off));
    float scale = fmaxf(amax / QMAX, SCALE_MIN);
    #pragma unroll
    for (int j = 0; j < 6; ++j) {
        int ci = lane + j * 64;
        float q = rintf(w[j] / scale);
        q = fminf(fmaxf(q, -QMAX), QMAX);
        float v = q * scale;
        int kk  = ci >> 5;
        int cis = ci & 31;
        int l   = (co & 15) | ((cis >> 3) << 4);
        int idx = (kk * 24 + (co >> 4)) * 512 + l * 8 + (cis & 7);
        wpk[idx] = (_Float16)v;
    }
}

// ---------------- kernel A (v4): DMA-staged depthwise 3x3 -------------------
// Block: 128 threads, one (n, c8 slab of 8 ch, 14-row group).
// Stage via global_load_lds (zero VGPR cost, 16 DMA ops all in flight):
// LDS = 8 ch x 256 quads; quad u of a channel: u==0 front pad, then rows of
// 15 quads (14 data + 1 end pad), tail pads. Pad/halo lanes read a zero page
// (per-lane GLOBAL address swizzle; LDS dest stays linear).
// Compute: thread = (row 0..13, wseg 0..6), 8 w x 8 ch, branch-free windows.

__global__ __launch_bounds__(128) void dw_kernel(
    const float* __restrict__ x, const float* __restrict__ dwq,
    const float* __restrict__ zpg, _Float16* __restrict__ ypk)
{
    __shared__ __align__(16) float xs[8 * CHF];   // 32 KB

    // 6144 blocks = 8 XCDs * 768, chunked swizzle; wg = (n*48 + c8)*4 + rg
    int bid = blockIdx.x;
    int wg = (bid & 7) * 768 + (bid >> 3);
    int rg = wg & 3;
    int t2 = wg >> 2;
    int c8 = t2 % 48, n = t2 / 48;
    const int h0 = rg * 14;
    const int tid = threadIdx.x;

    const float* xpl = x + ((size_t)n * CCH + (size_t)c8 * 8) * HW2;

    // ---- stage: 16 x global_load_lds(16B) per thread, linear LDS dest ----
    #pragma unroll
    for (int j = 0; j < 16; ++j) {
        const int ch = j >> 1;                    // uniform per j
        const unsigned u = (j & 1) * 128 + tid;   // quad index in channel
        const unsigned t = u - 1;                 // underflows for u==0 (ok)
        const unsigned r = t / 15u;               // staged row 0..15
        const unsigned q = t - r * 15u;           // quad in row 0..14
        const int srow = h0 - 1 + (int)r;
        const bool zero = (u == 0u) | (u > 240u) | (q == 14u) |
                          ((unsigned)srow > 55u);
        const float* src = zero ? (zpg + (tid & 63) * 4)
                                : (xpl + (size_t)ch * HW2 + srow * WW + q * 4);
        GLOAD_LDS16(src, xs + (j * 128 + (tid & 64)) * 4);
    }
    __syncthreads();

    if (tid >= 98) return;                 // 14 rows x 7 wsegs = 98 tasks

    const int row  = tid / 7;
    const int wseg = tid - row * 7;
    const int w0   = wseg * 8;
    const int qlo  = (w0 - 1) >> 2;        // -1,1,3,..,11 ; front pad covers -1

    half8 pk[8];
    #pragma unroll
    for (int ch = 0; ch < 8; ++ch) {
        const float* wq = dwq + (size_t)(c8 * 8 + ch) * 9;  // uniform -> s_loads
        float wv[9];
        #pragma unroll
        for (int k = 0; k < 9; ++k) wv[k] = wq[k];

        float a[8] = {0.f,0.f,0.f,0.f,0.f,0.f,0.f,0.f};
        #pragma unroll
        for (int dr = 0; dr < 3; ++dr) {
            const int base = ch * CHF + 4 + (row + dr) * ROWP + qlo * 4;
            f32x4 q0 = *(const f32x4*)&xs[base];
            f32x4 q1 = *(const f32x4*)&xs[base + 4];
            f32x4 q2 = *(const f32x4*)&xs[base + 8];
            f32x4 q3 = *(const f32x4*)&xs[base + 12];
            float win[16] = {q0.x,q0.y,q0.z,q0.w, q1.x,q1.y,q1.z,q1.w,
                             q2.x,q2.y,q2.z,q2.w, q3.x,q3.y,q3.z,q3.w};
            #pragma unroll
            for (int j0 = 0; j0 < 8; ++j0) {
                float s0 = a[j0];
                s0 = fmaf(win[3 + j0], wv[dr * 3 + 0], s0);
                s0 = fmaf(win[4 + j0], wv[dr * 3 + 1], s0);
                s0 = fmaf(win[5 + j0], wv[dr * 3 + 2], s0);
                a[j0] = s0;
            }
        }
        #pragma unroll
        for (int j0 = 0; j0 < 8; ++j0) pk[j0][ch] = (_Float16)a[j0];
    }

    // ---- stores: 8 half8 (16B each), channel-packed per position ----
    const int posb = (h0 + row) * WW + w0;
    _Float16* yn = ypk + (size_t)n * PB * YPB + (size_t)c8 * YSLAB;
    #pragma unroll
    for (int j0 = 0; j0 < 8; ++j0) {
        const int pos = posb + j0;
        *(half8*)(yn + (size_t)(pos >> 6) * YPB + (pos & 63) * 8) = pk[j0];
    }
}

// ---------------- kernel B: pointwise GEMM (384co x 384ci x 64pos/blk) ------
// Operand-swapped MFMA: D row=pos, col=co -> f32x4 = 4 consecutive positions
// -> vectorized dwordx4 epilogue stores.

__global__ __launch_bounds__(256) void pw_kernel(
    const _Float16* __restrict__ ypk, const _Float16* __restrict__ wpk,
    const float* __restrict__ bias, float* __restrict__ out)
{
    __shared__ __align__(16) _Float16 ysh[YPB];   // 48 KB

    int bid = blockIdx.x;                 // 1568 = 8 * 196
    int wg = (bid & 7) * 196 + (bid >> 3);
    int n = wg / PB, pb = wg % PB;

    const int t = threadIdx.x;
    const int lane = t & 63;
    const int g = __builtin_amdgcn_readfirstlane(t >> 6);

    // ---- stage y tile: identity copy of the packed 48KB blob ----
    const _Float16* yg = ypk + (size_t)(n * PB + pb) * YPB;
    #pragma unroll
    for (int j = 0; j < 12; ++j) {
        GLOAD_LDS16(yg + (j * 256 + t) * 8,
                    ysh + (size_t)(j * 256 + (t & 192)) * 8);
    }
    __syncthreads();

    // ---- K-loop ----
    const int lco = lane & 15;
    const int lkg = lane >> 4;
    const int cbf = g * 6;

    f32x4 acc[6][4];
    #pragma unroll
    for (int mc = 0; mc < 6; ++mc)
        #pragma unroll
        for (int np = 0; np < 4; ++np)
            acc[mc][np] = (f32x4){0.f, 0.f, 0.f, 0.f};

    for (int kk = 0; kk < 12; ++kk) {
        half8 wf[6];
        #pragma unroll
        for (int mc = 0; mc < 6; ++mc)
            wf[mc] = *(const half8*)(wpk + (size_t)(kk * 24 + cbf + mc) * 512 + lane * 8);
        half8 yf[4];
        #pragma unroll
        for (int np = 0; np < 4; ++np)
            yf[np] = *(const half8*)(ysh + kk * 2048 + lkg * 512 + (np * 16 + lco) * 8);
        #pragma unroll
        for (int mc = 0; mc < 6; ++mc)
            #pragma unroll
            for (int np = 0; np < 4; ++np)
                acc[mc][np] = __builtin_amdgcn_mfma_f32_16x16x32_f16(
                    yf[np], wf[mc], acc[mc][np], 0, 0, 0);   // swapped: row=pos
    }

    // ---- epilogue: bias + vectorized store (4 consecutive pos per lane) ----
    #pragma unroll
    for (int mc = 0; mc < 6; ++mc) {
        const int co = g * 96 + mc * 16 + lco;
        const float bv = bias[co];
        float* orow = out + (size_t)n * CCH * HW2 + (size_t)co * HW2
                          + (size_t)pb * 64 + lkg * 4;
        #pragma unroll
        for (int np = 0; np < 4; ++np) {
            f32x4 v = acc[mc][np];
            v.x += bv; v.y += bv; v.z += bv; v.w += bv;
            *(f32x4*)(orow + np * 16) = v;
        }
    }
}

// ---------------------------------------------------------------------------

extern "C" void kernel_launch(void* const* d_in, const int* in_sizes, int n_in,
                              void* d_out, int out_size, void* d_ws, size_t ws_size,
                              hipStream_t stream) {
    const float* x  = (const float*)d_in[0];
    const float* dw = (const float*)d_in[1];
    const float* pw = (const float*)d_in[2];
    const float* pb = (const float*)d_in[3];
    float* out = (float*)d_out;

    float*    dwq = (float*)d_ws;                         // 3456 f32
    float*    zpg = dwq + CCH * 9;                        // 1024 f32 zero page
    _Float16* wpk = (_Float16*)(zpg + 1024);              // 147456 fp16
    _Float16* ypk = wpk + (size_t)CCH * CCH;              // 38.5M fp16 (77 MB)

    quant_dw<<<2, 256, 0, stream>>>(dw, dwq, zpg);
    quant_pw<<<CCH, 64, 0, stream>>>(pw, wpk);

    dw_kernel<<<6144, 128, 0, stream>>>(x, dwq, zpg, ypk);
    pw_kernel<<<1568, 256, 0, stream>>>(ypk, wpk, pb, out);
}

// Round 8
// 147.372 us; speedup vs baseline: 1.0145x; 1.0145x over previous
//
#include <hip/hip_runtime.h>
#include <hip/hip_bf16.h>

#define CCH 384
#define HW2 3136
#define HH 56
#define WW 56
#define QMAX 7.0f
#define SCALE_MIN 2e-16f
#define PB 49            // 64-pos blocks per image
#define YSLAB 512        // elems per (pb,c8) slab: 64 pos * 8 ci
#define YPB 24576        // 48 * 512 elems per pos-block
#define ROWP 60          // padded LDS row stride (floats); pad [56..59] = 0
#define CHW 964          // per-channel LDS floats: 4 front pad + 16*60

typedef _Float16 half8 __attribute__((ext_vector_type(8)));
typedef float f32x4 __attribute__((ext_vector_type(4)));

// ---------------- quant kernels (Brevitas per-channel symmetric int4) -------

__global__ void quant_dw(const float* __restrict__ dw, float* __restrict__ dwq) {
    int c = blockIdx.x * blockDim.x + threadIdx.x;
    if (c >= CCH) return;
    float w[9];
    float amax = 0.f;
    #pragma unroll
    for (int j = 0; j < 9; ++j) {
        w[j] = dw[c * 9 + j];
        amax = fmaxf(amax, fabsf(w[j]));
    }
    float scale = fmaxf(amax / QMAX, SCALE_MIN);
    #pragma unroll
    for (int j = 0; j < 9; ++j) {
        float q = rintf(w[j] / scale);          // round half-even = jnp.round
        q = fminf(fmaxf(q, -QMAX), QMAX);
        dwq[c * 9 + j] = q * scale;
    }
}

// one block (64 threads) per output channel; fake-quant then pack fp16 into
// MFMA fragment layout: wpk[(ci/32)*24 + co/16][lane][8]
__global__ void quant_pw(const float* __restrict__ pw, _Float16* __restrict__ wpk) {
    int co = blockIdx.x;
    int lane = threadIdx.x;
    float w[6];
    float amax = 0.f;
    #pragma unroll
    for (int j = 0; j < 6; ++j) {
        w[j] = pw[co * CCH + lane + j * 64];
        amax = fmaxf(amax, fabsf(w[j]));
    }
    #pragma unroll
    for (int off = 32; off >= 1; off >>= 1)
        amax = fmaxf(amax, __shfl_xor(amax, off));
    float scale = fmaxf(amax / QMAX, SCALE_MIN);
    #pragma unroll
    for (int j = 0; j < 6; ++j) {
        int ci = lane + j * 64;
        float q = rintf(w[j] / scale);
        q = fminf(fmaxf(q, -QMAX), QMAX);
        float v = q * scale;
        int kk  = ci >> 5;
        int cis = ci & 31;
        int l   = (co & 15) | ((cis >> 3) << 4);
        int idx = (kk * 24 + (co >> 4)) * 512 + l * 8 + (cis & 7);
        wpk[idx] = (_Float16)v;
    }
}

// ---------------- kernel A (v5): rolling LDS-staged depthwise 3x3 -----------
// Block: 128 threads, one (n, c8 slab of 8 ch); loops over 4 row-groups.
// T14 pipeline: chunk t+1's 14 global float4 loads issue right after the
// post-write barrier, overlapping chunk t's compute+store. LDS single-buffer.

__global__ __launch_bounds__(128) void dw_kernel(
    const float* __restrict__ x, const float* __restrict__ dwq,
    _Float16* __restrict__ ypk)
{
    __shared__ __align__(16) float xs[8 * CHW];   // 30,848 B

    // 1536 blocks = 8 XCDs * 192, chunked swizzle; wg = n*48 + c8
    int bid = blockIdx.x;
    int wg = (bid & 7) * 192 + (bid >> 3);
    int c8 = wg % 48, n = wg / 48;
    const int tid = threadIdx.x;

    const float* xpl = x + ((size_t)n * CCH + (size_t)c8 * 8) * HW2;

    // ---- zero the pads (once; staging never overwrites them) ----
    {
        int s = tid >> 3, ch = tid & 7;                     // 16 rows x 8 ch
        *(f32x4*)&xs[ch * CHW + 4 + s * ROWP + 56] = (f32x4){0.f, 0.f, 0.f, 0.f};
        if (tid < 32) xs[(tid >> 2) * CHW + (tid & 3)] = 0.f;   // front pads
    }

    const int sch = tid >> 4, idx16 = tid & 15;   // staging role
    const float* src = xpl + (size_t)sch * HW2;

    const int row  = tid / 7;                      // compute role (tid<98)
    const int wseg = tid - row * 7;
    const int w0   = wseg * 8;
    const int qlo  = (w0 - 1) >> 2;

    _Float16* yn = ypk + (size_t)n * PB * YPB + (size_t)c8 * YSLAB;

    f32x4 v[14];
    // prologue: load chunk 0
    #pragma unroll
    for (int j = 0; j < 14; ++j) {
        const int gq = j * 16 + idx16;
        const int s = gq / 14, q = gq - s * 14;
        const int srow = -1 + s;
        const int crow = srow < 0 ? 0 : srow;
        f32x4 t = *(const f32x4*)(src + crow * WW + q * 4);
        if (srow != crow) t = (f32x4){0.f, 0.f, 0.f, 0.f};
        v[j] = t;
    }

    #pragma unroll
    for (int rg = 0; rg < 4; ++rg) {
        const int h0 = rg * 14;

        // ---- write staged chunk to LDS ----
        #pragma unroll
        for (int j = 0; j < 14; ++j) {
            const int gq = j * 16 + idx16;
            const int s = gq / 14, q = gq - s * 14;
            *(f32x4*)&xs[sch * CHW + 4 + s * ROWP + q * 4] = v[j];
        }
        __syncthreads();

        // ---- T14: issue next chunk's global loads before compute ----
        if (rg < 3) {
            const int h0n = h0 + 14;
            #pragma unroll
            for (int j = 0; j < 14; ++j) {
                const int gq = j * 16 + idx16;
                const int s = gq / 14, q = gq - s * 14;
                const int srow = h0n - 1 + s;
                const int crow = srow > 55 ? 55 : srow;
                f32x4 t = *(const f32x4*)(src + crow * WW + q * 4);
                if (srow != crow) t = (f32x4){0.f, 0.f, 0.f, 0.f};
                v[j] = t;
            }
        }

        // ---- compute 14 rows x 56 w x 8 ch from LDS ----
        if (tid < 98) {
            half8 pk[8];
            #pragma unroll
            for (int ch = 0; ch < 8; ++ch) {
                const float* wq = dwq + (size_t)(c8 * 8 + ch) * 9;
                float wv[9];
                #pragma unroll
                for (int k = 0; k < 9; ++k) wv[k] = wq[k];

                float a[8] = {0.f,0.f,0.f,0.f,0.f,0.f,0.f,0.f};
                #pragma unroll
                for (int dr = 0; dr < 3; ++dr) {
                    const int base = ch * CHW + 4 + (row + dr) * ROWP + qlo * 4;
                    f32x4 q0 = *(const f32x4*)&xs[base];
                    f32x4 q1 = *(const f32x4*)&xs[base + 4];
                    f32x4 q2 = *(const f32x4*)&xs[base + 8];
                    f32x4 q3 = *(const f32x4*)&xs[base + 12];
                    float win[16] = {q0.x,q0.y,q0.z,q0.w, q1.x,q1.y,q1.z,q1.w,
                                     q2.x,q2.y,q2.z,q2.w, q3.x,q3.y,q3.z,q3.w};
                    #pragma unroll
                    for (int j0 = 0; j0 < 8; ++j0) {
                        float s0 = a[j0];
                        s0 = fmaf(win[3 + j0], wv[dr * 3 + 0], s0);
                        s0 = fmaf(win[4 + j0], wv[dr * 3 + 1], s0);
                        s0 = fmaf(win[5 + j0], wv[dr * 3 + 2], s0);
                        a[j0] = s0;
                    }
                }
                #pragma unroll
                for (int j0 = 0; j0 < 8; ++j0) pk[j0][ch] = (_Float16)a[j0];
            }

            const int posb = (h0 + row) * WW + w0;
            #pragma unroll
            for (int j0 = 0; j0 < 8; ++j0) {
                const int pos = posb + j0;
                *(half8*)(yn + (size_t)(pos >> 6) * YPB + (pos & 63) * 8) = pk[j0];
            }
        }
        __syncthreads();   // before next chunk's ds_write overwrites
    }
}

// ---------------- kernel B: pointwise GEMM, LDS-free ------------------------
// y tile is read exactly once per block and the packed layout is perfectly
// coalesced (16 lanes x 16B contiguous) -> read straight from global (L3-hot).
// Operand-swapped MFMA: D row=pos -> f32x4 = 4 consecutive positions ->
// vectorized dwordx4 epilogue.

__global__ __launch_bounds__(256) void pw_kernel(
    const _Float16* __restrict__ ypk, const _Float16* __restrict__ wpk,
    const float* __restrict__ bias, float* __restrict__ out)
{
    int bid = blockIdx.x;                 // 1568 = 8 * 196
    int wg = (bid & 7) * 196 + (bid >> 3);
    int n = wg / PB, pb = wg % PB;

    const int t = threadIdx.x;
    const int lane = t & 63;
    const int g = __builtin_amdgcn_readfirstlane(t >> 6);

    const _Float16* yg = ypk + (size_t)(n * PB + pb) * YPB;

    const int lco = lane & 15;
    const int lkg = lane >> 4;
    const int cbf = g * 6;

    f32x4 acc[6][4];
    #pragma unroll
    for (int mc = 0; mc < 6; ++mc)
        #pragma unroll
        for (int np = 0; np < 4; ++np)
            acc[mc][np] = (f32x4){0.f, 0.f, 0.f, 0.f};

    for (int kk = 0; kk < 12; ++kk) {
        half8 wf[6];
        #pragma unroll
        for (int mc = 0; mc < 6; ++mc)
            wf[mc] = *(const half8*)(wpk + (size_t)(kk * 24 + cbf + mc) * 512 + lane * 8);
        half8 yf[4];
        #pragma unroll
        for (int np = 0; np < 4; ++np)
            yf[np] = *(const half8*)(yg + kk * 2048 + lkg * 512 + (np * 16 + lco) * 8);
        #pragma unroll
        for (int mc = 0; mc < 6; ++mc)
            #pragma unroll
            for (int np = 0; np < 4; ++np)
                acc[mc][np] = __builtin_amdgcn_mfma_f32_16x16x32_f16(
                    yf[np], wf[mc], acc[mc][np], 0, 0, 0);   // swapped: row=pos
    }

    // ---- epilogue: bias + vectorized store (4 consecutive pos per lane) ----
    #pragma unroll
    for (int mc = 0; mc < 6; ++mc) {
        const int co = g * 96 + mc * 16 + lco;
        const float bv = bias[co];
        float* orow = out + (size_t)n * CCH * HW2 + (size_t)co * HW2
                          + (size_t)pb * 64 + lkg * 4;
        #pragma unroll
        for (int np = 0; np < 4; ++np) {
            f32x4 v = acc[mc][np];
            v.x += bv; v.y += bv; v.z += bv; v.w += bv;
            *(f32x4*)(orow + np * 16) = v;
        }
    }
}

// ---------------------------------------------------------------------------

extern "C" void kernel_launch(void* const* d_in, const int* in_sizes, int n_in,
                              void* d_out, int out_size, void* d_ws, size_t ws_size,
                              hipStream_t stream) {
    const float* x  = (const float*)d_in[0];
    const float* dw = (const float*)d_in[1];
    const float* pw = (const float*)d_in[2];
    const float* pb = (const float*)d_in[3];
    float* out = (float*)d_out;

    float*    dwq = (float*)d_ws;                         // 3456 f32
    _Float16* wpk = (_Float16*)(dwq + CCH * 9);           // 147456 fp16
    _Float16* ypk = wpk + (size_t)CCH * CCH;              // 38.5M fp16 (77 MB)

    quant_dw<<<2, 256, 0, stream>>>(dw, dwq);
    quant_pw<<<CCH, 64, 0, stream>>>(pw, wpk);

    dw_kernel<<<1536, 128, 0, stream>>>(x, dwq, ypk);
    pw_kernel<<<1568, 256, 0, stream>>>(ypk, wpk, pb, out);
}

// Round 9
// 121.524 us; speedup vs baseline: 1.2303x; 1.2127x over previous
//
#include <hip/hip_runtime.h>
#include <hip/hip_bf16.h>

#define CCH 384
#define HW2 3136
#define HH 56
#define WW 56
#define QMAX 7.0f
#define SCALE_MIN 2e-16f
#define PB 49            // 64-pos blocks per image
#define YSLAB 512        // elems per (pb,c8) slab: 64 pos * 8 ci
#define YPB 24576        // 48 * 512 elems per pos-block

typedef _Float16 half8 __attribute__((ext_vector_type(8)));
typedef float f32x4 __attribute__((ext_vector_type(4)));

#define GLOAD_LDS16(g, l) __builtin_amdgcn_global_load_lds( \
    (const __attribute__((address_space(1))) void*)(g), \
    (__attribute__((address_space(3))) void*)(l), 16, 0, 0)

// ---------------- quant kernels (Brevitas per-channel symmetric int4) -------

__global__ void quant_dw(const float* __restrict__ dw, float* __restrict__ dwq) {
    int c = blockIdx.x * blockDim.x + threadIdx.x;
    if (c >= CCH) return;
    float w[9];
    float amax = 0.f;
    #pragma unroll
    for (int j = 0; j < 9; ++j) {
        w[j] = dw[c * 9 + j];
        amax = fmaxf(amax, fabsf(w[j]));
    }
    float scale = fmaxf(amax / QMAX, SCALE_MIN);
    #pragma unroll
    for (int j = 0; j < 9; ++j) {
        float q = rintf(w[j] / scale);          // round half-even = jnp.round
        q = fminf(fmaxf(q, -QMAX), QMAX);
        dwq[c * 9 + j] = q * scale;
    }
}

// one block (64 threads) per output channel; fake-quant then pack fp16 into
// MFMA fragment layout: wpk[(ci/32)*24 + co/16][lane][8]
__global__ void quant_pw(const float* __restrict__ pw, _Float16* __restrict__ wpk) {
    int co = blockIdx.x;
    int lane = threadIdx.x;
    float w[6];
    float amax = 0.f;
    #pragma unroll
    for (int j = 0; j < 6; ++j) {
        w[j] = pw[co * CCH + lane + j * 64];
        amax = fmaxf(amax, fabsf(w[j]));
    }
    #pragma unroll
    for (int off = 32; off >= 1; off >>= 1)
        amax = fmaxf(amax, __shfl_xor(amax, off));
    float scale = fmaxf(amax / QMAX, SCALE_MIN);
    #pragma unroll
    for (int j = 0; j < 6; ++j) {
        int ci = lane + j * 64;
        float q = rintf(w[j] / scale);
        q = fminf(fmaxf(q, -QMAX), QMAX);
        float v = q * scale;
        int kk  = ci >> 5;
        int cis = ci & 31;
        int l   = (co & 15) | ((cis >> 3) << 4);
        int idx = (kk * 24 + (co >> 4)) * 512 + l * 8 + (cis & 7);
        wpk[idx] = (_Float16)v;
    }
}

// ---------------- kernel A (v6): LDS-free column-streaming depthwise --------
// Wave-unit = (n, c8 slab of 8 ch, 14-row quarter). Lane = column w (0..55).
// Per step: 8 coalesced 224B row loads (1-row lookahead), w+-1 halo via
// shfl_up/down, 3-row register window slides vertically. x read once, wide.
// No LDS, no barriers. Weights pinned to SGPR via readfirstlane.

struct G8 { float l[8], c[8], r[8]; };

__device__ __forceinline__ void dw_load(const float* __restrict__ xc,
                                        float (&xn)[8], int srow, int wl) {
    if ((unsigned)srow < (unsigned)HH) {
        #pragma unroll
        for (int ch = 0; ch < 8; ++ch)
            xn[ch] = xc[(size_t)ch * HW2 + srow * WW + wl];
    } else {
        #pragma unroll
        for (int ch = 0; ch < 8; ++ch) xn[ch] = 0.f;
    }
}

__device__ __forceinline__ void dw_shuf(const float (&xn)[8], G8& g, int w) {
    #pragma unroll
    for (int ch = 0; ch < 8; ++ch) {
        float v = xn[ch];
        float xl = __shfl_up(v, 1);
        float xr = __shfl_down(v, 1);
        g.c[ch] = v;
        g.l[ch] = (w == 0) ? 0.f : xl;
        g.r[ch] = (w == WW - 1) ? 0.f : xr;
    }
}

__device__ __forceinline__ void dw_cs(const G8& ga, const G8& gb, const G8& gc,
                                      const float (&wq)[72], _Float16* yn,
                                      int orow, int w, bool act) {
    half8 hv;
    #pragma unroll
    for (int ch = 0; ch < 8; ++ch) {
        const int b = ch * 9;
        float a;
        a = ga.l[ch] * wq[b + 0];
        a = fmaf(ga.c[ch], wq[b + 1], a);
        a = fmaf(ga.r[ch], wq[b + 2], a);
        a = fmaf(gb.l[ch], wq[b + 3], a);
        a = fmaf(gb.c[ch], wq[b + 4], a);
        a = fmaf(gb.r[ch], wq[b + 5], a);
        a = fmaf(gc.l[ch], wq[b + 6], a);
        a = fmaf(gc.c[ch], wq[b + 7], a);
        a = fmaf(gc.r[ch], wq[b + 8], a);
        hv[ch] = (_Float16)a;
    }
    if (act) {
        const int pos = orow * WW + w;
        *(half8*)(yn + (size_t)(pos >> 6) * YPB + (pos & 63) * 8) = hv;
    }
}

#define DW_STEP(GA, GB, GC, XC_, XN_)                         \
    dw_load(xc, XN_, srow + 1, wl);                           \
    dw_shuf(XC_, GC, w);                                      \
    dw_cs(GA, GB, GC, wq, yn, srow - 1, w, act);              \
    ++srow;

__global__ __launch_bounds__(128) void dw_kernel(
    const float* __restrict__ x, const float* __restrict__ dwq,
    _Float16* __restrict__ ypk)
{
    // 3072 blocks x 2 waves = 6144 wave-units; XCD-chunked swizzle
    int bid = blockIdx.x;
    int wg = (bid & 7) * 384 + (bid >> 3);
    int uid = wg * 2 + (threadIdx.x >> 6);
    int quarter = uid & 3;
    int t2 = uid >> 2;
    int c8 = t2 % 48, n = t2 / 48;
    const int R0 = quarter * 14;

    const int w = threadIdx.x & 63;
    const int wl = w < WW ? w : WW - 1;
    const bool act = (w < WW);

    const float* xc = x + ((size_t)n * CCH + (size_t)c8 * 8) * HW2;
    _Float16* yn = ypk + (size_t)n * PB * YPB + (size_t)c8 * YSLAB;

    // weights -> SGPR (wave-uniform)
    float wq[72];
    const float* wsrc = dwq + c8 * 72;
    #pragma unroll
    for (int i = 0; i < 72; ++i)
        wq[i] = __uint_as_float(
            __builtin_amdgcn_readfirstlane(__float_as_uint(wsrc[i])));

    G8 g0, g1, g2;
    float x0[8], x1[8], xp[8];

    // prologue: rows R0-1, R0 into g0,g1; raw row R0+1 into x0
    if (R0 == 0) {
        #pragma unroll
        for (int ch = 0; ch < 8; ++ch) xp[ch] = 0.f;
    } else {
        dw_load(xc, xp, R0 - 1, wl);
    }
    dw_shuf(xp, g0, w);
    dw_load(xc, xp, R0, wl);
    dw_shuf(xp, g1, w);
    dw_load(xc, x0, R0 + 1, wl);
    int srow = R0 + 1;

    for (int it = 0; it < 2; ++it) {     // 12 steps
        DW_STEP(g0, g1, g2, x0, x1)
        DW_STEP(g1, g2, g0, x1, x0)
        DW_STEP(g2, g0, g1, x0, x1)
        DW_STEP(g0, g1, g2, x1, x0)
        DW_STEP(g1, g2, g0, x0, x1)
        DW_STEP(g2, g0, g1, x1, x0)
    }
    DW_STEP(g0, g1, g2, x0, x1)          // steps 13,14
    DW_STEP(g1, g2, g0, x1, x0)
}

// ---------------- kernel B: pointwise GEMM (384co x 384ci x 64pos/blk) ------
// r3 version: stage packed y tile (48KB) via global_load_lds, one barrier,
// pure ds_read_b128 + MFMA, scalar epilogue.

__global__ __launch_bounds__(256) void pw_kernel(
    const _Float16* __restrict__ ypk, const _Float16* __restrict__ wpk,
    const float* __restrict__ bias, float* __restrict__ out)
{
    __shared__ __align__(16) _Float16 ysh[YPB];   // 48 KB

    int bid = blockIdx.x;                 // 1568 = 8 * 196
    int wg = (bid & 7) * 196 + (bid >> 3);
    int n = wg / PB, pb = wg % PB;

    const int t = threadIdx.x;
    const int lane = t & 63;
    const int g = __builtin_amdgcn_readfirstlane(t >> 6);

    // ---- stage y tile: identity copy of the packed 48KB blob ----
    const _Float16* yg = ypk + (size_t)(n * PB + pb) * YPB;
    #pragma unroll
    for (int j = 0; j < 12; ++j) {
        GLOAD_LDS16(yg + (j * 256 + t) * 8,
                    ysh + (size_t)(j * 256 + (t & 192)) * 8);
    }
    __syncthreads();

    // ---- K-loop ----
    const int lco = lane & 15;
    const int lkg = lane >> 4;
    const int cbf = g * 6;

    f32x4 acc[6][4];
    #pragma unroll
    for (int mc = 0; mc < 6; ++mc)
        #pragma unroll
        for (int np = 0; np < 4; ++np)
            acc[mc][np] = (f32x4){0.f, 0.f, 0.f, 0.f};

    for (int kk = 0; kk < 12; ++kk) {
        half8 wf[6];
        #pragma unroll
        for (int mc = 0; mc < 6; ++mc)
            wf[mc] = *(const half8*)(wpk + (size_t)(kk * 24 + cbf + mc) * 512 + lane * 8);
        half8 yf[4];
        #pragma unroll
        for (int np = 0; np < 4; ++np)
            yf[np] = *(const half8*)(ysh + kk * 2048 + lkg * 512 + (np * 16 + lco) * 8);
        #pragma unroll
        for (int mc = 0; mc < 6; ++mc)
            #pragma unroll
            for (int np = 0; np < 4; ++np)
                acc[mc][np] = __builtin_amdgcn_mfma_f32_16x16x32_f16(
                    wf[mc], yf[np], acc[mc][np], 0, 0, 0);
    }

    // ---- epilogue: bias + store ----
    float* ob = out + (size_t)n * CCH * HW2 + (size_t)pb * 64;
    #pragma unroll
    for (int mc = 0; mc < 6; ++mc) {
        #pragma unroll
        for (int r = 0; r < 4; ++r) {
            const int co = g * 96 + mc * 16 + lkg * 4 + r;
            const float bv = bias[co];
            #pragma unroll
            for (int np = 0; np < 4; ++np)
                ob[(size_t)co * HW2 + np * 16 + lco] = acc[mc][np][r] + bv;
        }
    }
}

// ---------------------------------------------------------------------------

extern "C" void kernel_launch(void* const* d_in, const int* in_sizes, int n_in,
                              void* d_out, int out_size, void* d_ws, size_t ws_size,
                              hipStream_t stream) {
    const float* x  = (const float*)d_in[0];
    const float* dw = (const float*)d_in[1];
    const float* pw = (const float*)d_in[2];
    const float* pb = (const float*)d_in[3];
    float* out = (float*)d_out;

    float*    dwq = (float*)d_ws;                         // 3456 f32
    _Float16* wpk = (_Float16*)(dwq + CCH * 9);           // 147456 fp16
    _Float16* ypk = wpk + (size_t)CCH * CCH;              // 38.5M fp16 (77 MB)

    quant_dw<<<2, 256, 0, stream>>>(dw, dwq);
    quant_pw<<<CCH, 64, 0, stream>>>(pw, wpk);

    dw_kernel<<<3072, 128, 0, stream>>>(x, dwq, ypk);
    pw_kernel<<<1568, 256, 0, stream>>>(ypk, wpk, pb, out);
}

// Round 10
// 117.681 us; speedup vs baseline: 1.2705x; 1.0327x over previous
//
#include <hip/hip_runtime.h>
#include <hip/hip_bf16.h>

#define CCH 384
#define HW2 3136
#define HH 56
#define WW 56
#define QMAX 7.0f
#define SCALE_MIN 2e-16f
#define PB 49            // 64-pos blocks per image
#define YSLAB 512        // elems per (pb,c8) slab: 64 pos * 8 ci
#define YPB 24576        // 48 * 512 elems per pos-block

typedef _Float16 half8 __attribute__((ext_vector_type(8)));
typedef float f32x4 __attribute__((ext_vector_type(4)));

#define GLOAD_LDS16(g, l) __builtin_amdgcn_global_load_lds( \
    (const __attribute__((address_space(1))) void*)(g), \
    (__attribute__((address_space(3))) void*)(l), 16, 0, 0)

// ---------------- quant kernels (Brevitas per-channel symmetric int4) -------

__global__ void quant_dw(const float* __restrict__ dw, float* __restrict__ dwq) {
    int c = blockIdx.x * blockDim.x + threadIdx.x;
    if (c >= CCH) return;
    float w[9];
    float amax = 0.f;
    #pragma unroll
    for (int j = 0; j < 9; ++j) {
        w[j] = dw[c * 9 + j];
        amax = fmaxf(amax, fabsf(w[j]));
    }
    float scale = fmaxf(amax / QMAX, SCALE_MIN);
    #pragma unroll
    for (int j = 0; j < 9; ++j) {
        float q = rintf(w[j] / scale);          // round half-even = jnp.round
        q = fminf(fmaxf(q, -QMAX), QMAX);
        dwq[c * 9 + j] = q * scale;
    }
}

// one block (64 threads) per output channel; fake-quant then pack fp16 into
// MFMA fragment layout: wpk[(ci/32)*24 + co/16][lane][8]
__global__ void quant_pw(const float* __restrict__ pw, _Float16* __restrict__ wpk) {
    int co = blockIdx.x;
    int lane = threadIdx.x;
    float w[6];
    float amax = 0.f;
    #pragma unroll
    for (int j = 0; j < 6; ++j) {
        w[j] = pw[co * CCH + lane + j * 64];
        amax = fmaxf(amax, fabsf(w[j]));
    }
    #pragma unroll
    for (int off = 32; off >= 1; off >>= 1)
        amax = fmaxf(amax, __shfl_xor(amax, off));
    float scale = fmaxf(amax / QMAX, SCALE_MIN);
    #pragma unroll
    for (int j = 0; j < 6; ++j) {
        int ci = lane + j * 64;
        float q = rintf(w[j] / scale);
        q = fminf(fmaxf(q, -QMAX), QMAX);
        float v = q * scale;
        int kk  = ci >> 5;
        int cis = ci & 31;
        int l   = (co & 15) | ((cis >> 3) << 4);
        int idx = (kk * 24 + (co >> 4)) * 512 + l * 8 + (cis & 7);
        wpk[idx] = (_Float16)v;
    }
}

// ---------------- kernel A (v6.1): column-streaming depthwise, depth-2 ------
// Wave-unit = (n, c8 slab of 8 ch, 14-row quarter). Lane = column w (0..55).
// Raw-row ring r0..r3 (4 deep): load row t+3 at iter k while shuffling the
// row loaded at iter k-2 -> two steps (~600cyc) of L3 latency cover.
// No LDS, no barriers. Weights pinned to SGPR via readfirstlane.

struct G8 { float l[8], c[8], r[8]; };

__device__ __forceinline__ void dw_load(const float* __restrict__ xc,
                                        float (&xn)[8], int srow, int wl) {
    if ((unsigned)srow < (unsigned)HH) {
        #pragma unroll
        for (int ch = 0; ch < 8; ++ch)
            xn[ch] = xc[(size_t)ch * HW2 + srow * WW + wl];
    } else {
        #pragma unroll
        for (int ch = 0; ch < 8; ++ch) xn[ch] = 0.f;
    }
}

__device__ __forceinline__ void dw_shuf(const float (&xn)[8], G8& g, int w) {
    #pragma unroll
    for (int ch = 0; ch < 8; ++ch) {
        float v = xn[ch];
        float xl = __shfl_up(v, 1);
        float xr = __shfl_down(v, 1);
        g.c[ch] = v;
        g.l[ch] = (w == 0) ? 0.f : xl;
        g.r[ch] = (w == WW - 1) ? 0.f : xr;
    }
}

__device__ __forceinline__ void dw_cs(const G8& ga, const G8& gb, const G8& gc,
                                      const float (&wq)[72], _Float16* yn,
                                      int orow, int w, bool act) {
    half8 hv;
    #pragma unroll
    for (int ch = 0; ch < 8; ++ch) {
        const int b = ch * 9;
        float a;
        a = ga.l[ch] * wq[b + 0];
        a = fmaf(ga.c[ch], wq[b + 1], a);
        a = fmaf(ga.r[ch], wq[b + 2], a);
        a = fmaf(gb.l[ch], wq[b + 3], a);
        a = fmaf(gb.c[ch], wq[b + 4], a);
        a = fmaf(gb.r[ch], wq[b + 5], a);
        a = fmaf(gc.l[ch], wq[b + 6], a);
        a = fmaf(gc.c[ch], wq[b + 7], a);
        a = fmaf(gc.r[ch], wq[b + 8], a);
        hv[ch] = (_Float16)a;
    }
    if (act) {
        const int pos = orow * WW + w;
        *(half8*)(yn + (size_t)(pos >> 6) * YPB + (pos & 63) * 8) = hv;
    }
}

// iter k: load row R0+3+k -> RL; shuffle RS (row R0+1+k) -> GS;
// compute output row R0+k from (GA,GB,GC).
#define DW_IT(K, RL, RS, GS, GA, GB, GC, DOLOAD)              \
    if (DOLOAD) dw_load(xc, RL, R0 + 3 + (K), wl);            \
    dw_shuf(RS, GS, w);                                       \
    dw_cs(GA, GB, GC, wq, yn, R0 + (K), w, act);

__global__ __launch_bounds__(128) void dw_kernel(
    const float* __restrict__ x, const float* __restrict__ dwq,
    _Float16* __restrict__ ypk)
{
    // 3072 blocks x 2 waves = 6144 wave-units; XCD-chunked swizzle
    int bid = blockIdx.x;
    int wg = (bid & 7) * 384 + (bid >> 3);
    int uid = wg * 2 + (threadIdx.x >> 6);
    int quarter = uid & 3;
    int t2 = uid >> 2;
    int c8 = t2 % 48, n = t2 / 48;
    const int R0 = quarter * 14;

    const int w = threadIdx.x & 63;
    const int wl = w < WW ? w : WW - 1;
    const bool act = (w < WW);

    const float* xc = x + ((size_t)n * CCH + (size_t)c8 * 8) * HW2;
    _Float16* yn = ypk + (size_t)n * PB * YPB + (size_t)c8 * YSLAB;

    // weights -> SGPR (wave-uniform)
    float wq[72];
    const float* wsrc = dwq + c8 * 72;
    #pragma unroll
    for (int i = 0; i < 72; ++i)
        wq[i] = __uint_as_float(
            __builtin_amdgcn_readfirstlane(__float_as_uint(wsrc[i])));

    float r0[8], r1[8], r2[8], r3[8];
    G8 g0, g1, g2;

    // prologue: issue rows R0-1..R0+2 as one independent batch
    if (R0 == 0) {
        #pragma unroll
        for (int ch = 0; ch < 8; ++ch) r0[ch] = 0.f;
    } else {
        dw_load(xc, r0, R0 - 1, wl);
    }
    dw_load(xc, r1, R0, wl);
    dw_load(xc, r2, R0 + 1, wl);
    dw_load(xc, r3, R0 + 2, wl);
    dw_shuf(r0, g0, w);
    dw_shuf(r1, g1, w);

    DW_IT(0,  r0, r2, g2, g0, g1, g2, true)
    DW_IT(1,  r1, r3, g0, g1, g2, g0, true)
    DW_IT(2,  r2, r0, g1, g2, g0, g1, true)
    DW_IT(3,  r3, r1, g2, g0, g1, g2, true)
    DW_IT(4,  r0, r2, g0, g1, g2, g0, true)
    DW_IT(5,  r1, r3, g1, g2, g0, g1, true)
    DW_IT(6,  r2, r0, g2, g0, g1, g2, true)
    DW_IT(7,  r3, r1, g0, g1, g2, g0, true)
    DW_IT(8,  r0, r2, g1, g2, g0, g1, true)
    DW_IT(9,  r1, r3, g2, g0, g1, g2, true)
    DW_IT(10, r2, r0, g0, g1, g2, g0, true)
    DW_IT(11, r3, r1, g1, g2, g0, g1, true)
    DW_IT(12, r0, r2, g2, g0, g1, g2, false)
    DW_IT(13, r1, r3, g0, g1, g2, g0, false)
}

// ---------------- kernel B: pointwise GEMM (384co x 384ci x 64pos/blk) ------
// Stage packed y tile (48KB) via global_load_lds, one barrier, pure
// ds_read_b128 + MFMA, scalar epilogue.

__global__ __launch_bounds__(256) void pw_kernel(
    const _Float16* __restrict__ ypk, const _Float16* __restrict__ wpk,
    const float* __restrict__ bias, float* __restrict__ out)
{
    __shared__ __align__(16) _Float16 ysh[YPB];   // 48 KB

    int bid = blockIdx.x;                 // 1568 = 8 * 196
    int wg = (bid & 7) * 196 + (bid >> 3);
    int n = wg / PB, pb = wg % PB;

    const int t = threadIdx.x;
    const int lane = t & 63;
    const int g = __builtin_amdgcn_readfirstlane(t >> 6);

    // ---- stage y tile: identity copy of the packed 48KB blob ----
    const _Float16* yg = ypk + (size_t)(n * PB + pb) * YPB;
    #pragma unroll
    for (int j = 0; j < 12; ++j) {
        GLOAD_LDS16(yg + (j * 256 + t) * 8,
                    ysh + (size_t)(j * 256 + (t & 192)) * 8);
    }
    __syncthreads();

    // ---- K-loop ----
    const int lco = lane & 15;
    const int lkg = lane >> 4;
    const int cbf = g * 6;

    f32x4 acc[6][4];
    #pragma unroll
    for (int mc = 0; mc < 6; ++mc)
        #pragma unroll
        for (int np = 0; np < 4; ++np)
            acc[mc][np] = (f32x4){0.f, 0.f, 0.f, 0.f};

    for (int kk = 0; kk < 12; ++kk) {
        half8 wf[6];
        #pragma unroll
        for (int mc = 0; mc < 6; ++mc)
            wf[mc] = *(const half8*)(wpk + (size_t)(kk * 24 + cbf + mc) * 512 + lane * 8);
        half8 yf[4];
        #pragma unroll
        for (int np = 0; np < 4; ++np)
            yf[np] = *(const half8*)(ysh + kk * 2048 + lkg * 512 + (np * 16 + lco) * 8);
        #pragma unroll
        for (int mc = 0; mc < 6; ++mc)
            #pragma unroll
            for (int np = 0; np < 4; ++np)
                acc[mc][np] = __builtin_amdgcn_mfma_f32_16x16x32_f16(
                    wf[mc], yf[np], acc[mc][np], 0, 0, 0);
    }

    // ---- epilogue: bias + store ----
    float* ob = out + (size_t)n * CCH * HW2 + (size_t)pb * 64;
    #pragma unroll
    for (int mc = 0; mc < 6; ++mc) {
        #pragma unroll
        for (int r = 0; r < 4; ++r) {
            const int co = g * 96 + mc * 16 + lkg * 4 + r;
            const float bv = bias[co];
            #pragma unroll
            for (int np = 0; np < 4; ++np)
                ob[(size_t)co * HW2 + np * 16 + lco] = acc[mc][np][r] + bv;
        }
    }
}

// ---------------------------------------------------------------------------

extern "C" void kernel_launch(void* const* d_in, const int* in_sizes, int n_in,
                              void* d_out, int out_size, void* d_ws, size_t ws_size,
                              hipStream_t stream) {
    const float* x  = (const float*)d_in[0];
    const float* dw = (const float*)d_in[1];
    const float* pw = (const float*)d_in[2];
    const float* pb = (const float*)d_in[3];
    float* out = (float*)d_out;

    float*    dwq = (float*)d_ws;                         // 3456 f32
    _Float16* wpk = (_Float16*)(dwq + CCH * 9);           // 147456 fp16
    _Float16* ypk = wpk + (size_t)CCH * CCH;              // 38.5M fp16 (77 MB)

    quant_dw<<<2, 256, 0, stream>>>(dw, dwq);
    quant_pw<<<CCH, 64, 0, stream>>>(pw, wpk);

    dw_kernel<<<3072, 128, 0, stream>>>(x, dwq, ypk);
    pw_kernel<<<1568, 256, 0, stream>>>(ypk, wpk, pb, out);
}